// Round 6
// baseline (273.969 us; speedup 1.0000x reference)
//
#include <hip/hip_runtime.h>
#include <hip/hip_bf16.h>
#include <cstdint>

typedef _Float16 f16;
typedef f16 f16x8 __attribute__((ext_vector_type(8)));
typedef f16 f16x4 __attribute__((ext_vector_type(4)));
typedef float f32x4 __attribute__((ext_vector_type(4)));

#define MFMA16(a, b, c) __builtin_amdgcn_mfma_f32_16x16x32_f16((a), (b), (c), 0, 0, 0)

constexpr int Bc = 4, Sc = 2048, Dc = 1024, Hc = 16, DHc = 64;

typedef __attribute__((address_space(1))) const uint32_t gbl_u32;
typedef __attribute__((address_space(3))) uint32_t lds_u32;
__device__ __forceinline__ void gld_lds16(const void* g, void* l) {
  __builtin_amdgcn_global_load_lds((gbl_u32*)g, (lds_u32*)l, 16, 0, 0);
}

// ---------------------------------------------------------------------------
// Kernel 1: cast+transpose weights: W fp32 [K=1024][N=1024] -> Wt f16 [z][N][K]
// (viewed by the GEMM as one [3072][1024] B^T matrix)
// ---------------------------------------------------------------------------
__global__ __launch_bounds__(256) void cast_w_kernel(
    const float* __restrict__ Wq, const float* __restrict__ Wk,
    const float* __restrict__ Wv, f16* __restrict__ Wt) {
  __shared__ __align__(16) f16 T[64][66];
  const int z = blockIdx.z;
  const float* W = (z == 0) ? Wq : (z == 1) ? Wk : Wv;
  const int n0 = blockIdx.x * 64, k0 = blockIdx.y * 64;
  const int t = threadIdx.x;
#pragma unroll
  for (int p = 0; p < 4; p++) {
    int idx = t + p * 256;
    int r = idx >> 4, c = idx & 15;
    float4 v = *(const float4*)(W + (size_t)(k0 + r) * Dc + n0 + c * 4);
    T[r][c * 4 + 0] = (f16)v.x;
    T[r][c * 4 + 1] = (f16)v.y;
    T[r][c * 4 + 2] = (f16)v.z;
    T[r][c * 4 + 3] = (f16)v.w;
  }
  __syncthreads();
#pragma unroll
  for (int p = 0; p < 2; p++) {
    int idx = t + p * 256;
    int n = idx >> 3, c = idx & 7;
    f16x8 tmp;
#pragma unroll
    for (int j = 0; j < 8; j++) tmp[j] = T[c * 8 + j][n];
    *(f16x8*)(Wt + ((size_t)z * Dc + n0 + n) * Dc + k0 + c * 8) = tmp;
  }
}

// ---------------------------------------------------------------------------
// Kernel 1b: cast X fp32 -> f16.
// ---------------------------------------------------------------------------
__global__ __launch_bounds__(256) void cast_x_kernel(const float* __restrict__ X,
                                                     f16* __restrict__ X16) {
  size_t i = ((size_t)blockIdx.x * 256 + threadIdx.x) * 8;
  float4 a = *(const float4*)(X + i);
  float4 b = *(const float4*)(X + i + 4);
  f16x8 h;
  h[0] = (f16)a.x; h[1] = (f16)a.y; h[2] = (f16)a.z; h[3] = (f16)a.w;
  h[4] = (f16)b.x; h[5] = (f16)b.y; h[6] = (f16)b.z; h[7] = (f16)b.w;
  *(f16x8*)(X16 + i) = h;
}

// ---------------------------------------------------------------------------
// Kernel 2 (R4): fused QKV GEMM, ONE launch (1536 blocks, restores machine
// fill lost in the R3 split), BK=64 + source-XOR-swizzled LDS, frags read
// PER-KK-HALF (8 live frags, not 16 — R3's 64 live frag VGPRs likely cost
// a wave/SIMD of occupancy). Dual epilogue: z<2 computes C^T (r runs along
// d -> f16x4 pack along d), z==2 original orientation (packs along s).
// Swizzle involution: staged(row,i) holds global(row, i^(row&7)); frags
// read octet (o^(row&7)) -> banks spread 8-wide, 2-way = free.
// ---------------------------------------------------------------------------
__global__ __launch_bounds__(256) void qkv_gemm_kernel(
    const f16* __restrict__ X16, const f16* __restrict__ Wt,
    const float* __restrict__ bq, const float* __restrict__ bk,
    const float* __restrict__ bv, f16* __restrict__ Qo, f16* __restrict__ Ko,
    f16* __restrict__ Vo) {
  const int lin = blockIdx.x;               // 1536 blocks
  const int xcd = lin & 7, jj = lin >> 3;   // jj in [0,192)
  const int bn = jj >> 3;                   // 0..23 (n-tile over fused N=3072)
  const int bm = (xcd << 3) | (jj & 7);     // 0..63 (m-tile, innermost)
  const int z = bn >> 3;
  const int n0 = (bn & 7) * 128;            // col base within this z
  const int m0 = bm * 128;
  const f16* W = Wt + (size_t)bn * 128 * Dc;
  const float* bias = (z == 0) ? bq : (z == 1) ? bk : bv;
  const bool zqk = (z != 2);

  __shared__ __align__(16) f16 Xs[128 * 64];
  __shared__ __align__(16) f16 Ws[128 * 64];

  const int t = threadIdx.x;
  const int wave = t >> 6, lane = t & 63;
  const int l16 = lane & 15, quad = lane >> 4;
  const int wm = (wave >> 1) * 64, wn = (wave & 1) * 64;

  f32x4 acc[4][4];  // z<2: [nt][mt] (C^T); z==2: [mt][nt]
#pragma unroll
  for (int i = 0; i < 4; i++)
#pragma unroll
    for (int j = 0; j < 4; j++) acc[i][j] = (f32x4){0.f, 0.f, 0.f, 0.f};

  for (int k0 = 0; k0 < Dc; k0 += 64) {
#pragma unroll
    for (int p = 0; p < 4; p++) {
      int i = p * 256 + wave * 64 + lane;   // 1024 octets per matrix
      int row = i >> 3, oct = i & 7;
      int so = (oct ^ (row & 7)) * 8;       // pre-swizzled SOURCE column
      gld_lds16(X16 + (size_t)(m0 + row) * Dc + k0 + so, (f16*)Xs + (size_t)i * 8);
      gld_lds16(W + (size_t)row * Dc + k0 + so, (f16*)Ws + (size_t)i * 8);
    }
    __syncthreads();

#pragma unroll
    for (int kk = 0; kk < 2; kk++) {
      f16x8 aF[4], bF[4];
#pragma unroll
      for (int mt = 0; mt < 4; mt++) {
        int r = wm + mt * 16 + l16;
        aF[mt] = *(const f16x8*)(&Xs[r * 64 + (((kk * 4 + quad) ^ (r & 7)) * 8)]);
      }
#pragma unroll
      for (int nt = 0; nt < 4; nt++) {
        int r = wn + nt * 16 + l16;
        bF[nt] = *(const f16x8*)(&Ws[r * 64 + (((kk * 4 + quad) ^ (r & 7)) * 8)]);
      }
      if (zqk) {
#pragma unroll
        for (int nt = 0; nt < 4; nt++)
#pragma unroll
          for (int mt = 0; mt < 4; mt++)
            acc[nt][mt] = MFMA16(bF[nt], aF[mt], acc[nt][mt]);
      } else {
#pragma unroll
        for (int mt = 0; mt < 4; mt++)
#pragma unroll
          for (int nt = 0; nt < 4; nt++)
            acc[mt][nt] = MFMA16(aF[mt], bF[nt], acc[mt][nt]);
      }
    }
    __syncthreads();
  }

  if (zqk) {
    // C^T epilogue: row(quad*4+r) = d, col(l16) = s -> f16x4 pack along d
    f16* O = (z == 0) ? Qo : Ko;
    const float sc = (z == 0) ? 0.18033688011112042f : 1.0f;  // Q: 0.125*log2e
    const int h = (n0 + wn) >> 6;
#pragma unroll
    for (int nt = 0; nt < 4; nt++) {
      int cb = n0 + wn + nt * 16 + quad * 4;
      float4 bv4 = *(const float4*)(bias + cb);
      int d0 = nt * 16 + quad * 4;
#pragma unroll
      for (int mt = 0; mt < 4; mt++) {
        int m = m0 + wm + mt * 16 + l16;
        int b = m >> 11, s = m & 2047;
        f16x4 pk;
        pk[0] = (f16)((acc[nt][mt][0] + bv4.x) * sc);
        pk[1] = (f16)((acc[nt][mt][1] + bv4.y) * sc);
        pk[2] = (f16)((acc[nt][mt][2] + bv4.z) * sc);
        pk[3] = (f16)((acc[nt][mt][3] + bv4.w) * sc);
        *(f16x4*)(O + (((size_t)(b * Hc + h)) * Sc + s) * DHc + d0) = pk;
      }
    }
  } else {
    // V epilogue: r runs along s -> f16x4 pack along s into Vt [bh][d][s]
#pragma unroll
    for (int nt = 0; nt < 4; nt++) {
      int col = n0 + wn + nt * 16 + l16;
      float bval = bias[col];
      int h = col >> 6, d = col & 63;
#pragma unroll
      for (int mt = 0; mt < 4; mt++) {
        int m = m0 + wm + mt * 16 + quad * 4;
        int b = m >> 11, sbase = m & 2047;
        f16x4 pk;
#pragma unroll
        for (int r = 0; r < 4; r++) pk[r] = (f16)(acc[mt][nt][r] + bval);
        *(f16x4*)(Vo + (((size_t)(b * Hc + h)) * DHc + d) * Sc + sbase) = pk;
      }
    }
  }
}

// ---------------------------------------------------------------------------
// Kernel 3 (R4): flash attention, 64 QUERIES PER WAVE (4 m-tiles).
// R3 analysis: LDS pipe is the largest consumer (20 b128/wave/chunk serving
// only 32 queries; MfmaUtil 34, VALU 51, HBM 10%). Doubling the per-wave
// query tile halves LDS reads AND stage traffic per query. To keep VGPRs
// ~180 (2 waves/SIMD), each 64-key chunk is processed as 2 x 32-key halves:
// ka (4 frags) and pa[4] live only within a half. cvt_pkrtz packs
// 2 f32->2xf16 in one VALU op (returns __fp16 vector; cast elementwise).
// Key permutation (unchanged): staged row k holds global key phys(k),
// [n1 n0 q1 q0 r1 r0] -> [n1 q1 q0 n0 r1 r0]; softmax/PV/mask commute.
// grid: 512 blocks = 2/CU; lin&7 = XCD, bh innermost (K/V L2-resident).
// ---------------------------------------------------------------------------
__global__ __launch_bounds__(256) void flash_kernel(
    const f16* __restrict__ Q, const f16* __restrict__ K,
    const f16* __restrict__ Vt, const float* __restrict__ mask,
    float* __restrict__ out) {
  const int lin = blockIdx.x;               // 512 blocks
  const int xcd = lin & 7, jj = lin >> 3;   // jj in [0,64)
  const int bh = (xcd << 3) | (jj & 7);     // 0..63 (inner: bh cycles fastest)
  const int qt = jj >> 3;                   // 0..7
  const int b = bh >> 4, h = bh & 15;
  const int t = threadIdx.x;
  const int wave = t >> 6, lane = t & 63;
  const int l16 = lane & 15, quad = lane >> 4;
  const int qbase = qt * 256 + wave * 64;   // 64 queries per wave

  __shared__ __align__(16) f16 Ks[2][4096];  // [buf][dhHalf*2048+row*32+oct*8]
  __shared__ __align__(16) f16 Vs[2][4096];  // [buf][kHalf*2048+dh*32+oct*8]
  __shared__ __align__(16) float Ms[2048];   // mask row * log2(e)

  const f16* Kb = K + (size_t)bh * Sc * DHc;
  const f16* Vb = Vt + (size_t)bh * DHc * Sc;

  constexpr float L2E = 1.44269504088896340736f;

  // swizzled b128 read position (same for K and V frags)
  const int qsw8 = (quad ^ ((l16 >> 1) & 3)) * 8;

  // hoisted staging state (octet i -> dhHalf=i>>8, row=(i>>2)&63, q8=i&3
  // holds global octet q8^((row>>1)&3); K rows bit-shuffle permuted).
  const f16* kp[2];
  const f16* vp[2];
  int ldsOff[2];
#pragma unroll
  for (int p = 0; p < 2; p++) {
    int cb = p * 256 + wave * 64;  // wave-uniform octet base
    int i = cb + lane;
    int half = i >> 8, row = (i >> 2) & 63, q8 = i & 3;
    int q8g = q8 ^ ((row >> 1) & 3);
    int g = (row & 32) | ((row & 12) << 1) | ((row & 16) >> 2) | (row & 3);
    kp[p] = Kb + (size_t)g * DHc + half * 32 + q8g * 8;
    vp[p] = Vb + (size_t)row * Sc + half * 32 + q8g * 8;
    ldsOff[p] = cb * 8;
  }
  auto stage = [&](int buf) {
#pragma unroll
    for (int p = 0; p < 2; p++) {
      gld_lds16(kp[p], (f16*)Ks + buf * 4096 + ldsOff[p]);
      gld_lds16(vp[p], (f16*)Vs + buf * 4096 + ldsOff[p]);
      kp[p] += 64 * DHc;
      vp[p] += 64;
    }
  };

  // Q B-frags for 4 m-tiles; pre-scaled by 0.125*log2(e) in the GEMM.
  f16x8 qa[4][2];
#pragma unroll
  for (int mt = 0; mt < 4; mt++) {
    const f16* qb = Q + ((size_t)bh * Sc + qbase + mt * 16 + l16) * DHc;
    qa[mt][0] = *(const f16x8*)(qb + quad * 8);
    qa[mt][1] = *(const f16x8*)(qb + 32 + quad * 8);
  }

  // all-ones B-frag for the l row-sum MFMAs
  f16x8 ones;
#pragma unroll
  for (int j = 0; j < 8; j++) ones[j] = (f16)1.0f;

  // prologue: stage chunk 0; fill mask LDS (pre-scaled into exp2 domain)
  stage(0);
  {
    const float* mrow = mask + (size_t)b * Sc + t * 8;
    float4 a0 = *(const float4*)(mrow);
    float4 a1 = *(const float4*)(mrow + 4);
    *(f32x4*)(&Ms[t * 8]) = (f32x4){a0.x * L2E, a0.y * L2E, a0.z * L2E, a0.w * L2E};
    *(f32x4*)(&Ms[t * 8 + 4]) = (f32x4){a1.x * L2E, a1.y * L2E, a1.z * L2E, a1.w * L2E};
  }
  __syncthreads();

  f32x4 lacc[4];
  f32x4 o[4][4];
#pragma unroll
  for (int mt = 0; mt < 4; mt++) {
    lacc[mt] = (f32x4){0.f, 0.f, 0.f, 0.f};
#pragma unroll
    for (int dt = 0; dt < 4; dt++) o[mt][dt] = (f32x4){0.f, 0.f, 0.f, 0.f};
  }

  for (int c = 0; c < 32; c++) {
    const int buf = c & 1;
    if (c < 31) stage(buf ^ 1);
    const int mb = c * 64 + quad * 8;

#pragma unroll
    for (int kb = 0; kb < 2; kb++) {  // 32-key half of the chunk
      // mask C-init for key groups nt = 2kb, 2kb+1 (broadcast LDS reads)
      f32x4 mi0 = *(const f32x4*)(&Ms[mb + kb * 32]);
      f32x4 mi1 = *(const f32x4*)(&Ms[mb + kb * 32 + 4]);
      // K A-frags for the 2 staged key groups of this half
      int rb0 = ((2 * kb) * 16 + l16) * 32 + qsw8;
      int rb1 = ((2 * kb + 1) * 16 + l16) * 32 + qsw8;
      f16x8 ka00 = *(const f16x8*)(&Ks[buf][rb0]);
      f16x8 ka01 = *(const f16x8*)(&Ks[buf][2048 + rb0]);
      f16x8 ka10 = *(const f16x8*)(&Ks[buf][rb1]);
      f16x8 ka11 = *(const f16x8*)(&Ks[buf][2048 + rb1]);

      f16x8 pa[4];
#pragma unroll
      for (int mt = 0; mt < 4; mt++) {
        f32x4 s0 = mi0, s1 = mi1;
        s0 = MFMA16(ka00, qa[mt][0], s0);
        s0 = MFMA16(ka01, qa[mt][1], s0);
        s1 = MFMA16(ka10, qa[mt][0], s1);
        s1 = MFMA16(ka11, qa[mt][1], s1);
        auto e0 = __builtin_amdgcn_cvt_pkrtz(__builtin_amdgcn_exp2f(s0[0]),
                                             __builtin_amdgcn_exp2f(s0[1]));
        auto e1 = __builtin_amdgcn_cvt_pkrtz(__builtin_amdgcn_exp2f(s0[2]),
                                             __builtin_amdgcn_exp2f(s0[3]));
        auto e2 = __builtin_amdgcn_cvt_pkrtz(__builtin_amdgcn_exp2f(s1[0]),
                                             __builtin_amdgcn_exp2f(s1[1]));
        auto e3 = __builtin_amdgcn_cvt_pkrtz(__builtin_amdgcn_exp2f(s1[2]),
                                             __builtin_amdgcn_exp2f(s1[3]));
        f16x8 p;
        p[0] = (f16)e0[0]; p[1] = (f16)e0[1]; p[2] = (f16)e1[0]; p[3] = (f16)e1[1];
        p[4] = (f16)e2[0]; p[5] = (f16)e2[1]; p[6] = (f16)e3[0]; p[7] = (f16)e3[1];
        pa[mt] = p;
        lacc[mt] = MFMA16(p, ones, lacc[mt]);  // l row-sum on MFMA pipe
      }

      // PV for this key-half: V frags shared by all 4 m-tiles
#pragma unroll
      for (int dt = 0; dt < 4; dt++) {
        int rb = (dt * 16 + l16) * 32 + qsw8;
        f16x8 v = *(const f16x8*)(&Vs[buf][kb * 2048 + rb]);
        o[0][dt] = MFMA16(pa[0], v, o[0][dt]);
        o[1][dt] = MFMA16(pa[1], v, o[1][dt]);
        o[2][dt] = MFMA16(pa[2], v, o[2][dt]);
        o[3][dt] = MFMA16(pa[3], v, o[3][dt]);
      }
    }

    __syncthreads();
  }

  // ---- epilogue: lacc D-layout rows (quad*4+r) == o rows; no shuffles ----
#pragma unroll
  for (int mt = 0; mt < 4; mt++) {
    float inv[4];
#pragma unroll
    for (int r = 0; r < 4; r++) inv[r] = 1.0f / lacc[mt][r];
#pragma unroll
    for (int dt = 0; dt < 4; dt++) {
      int col = h * 64 + dt * 16 + l16;
#pragma unroll
      for (int r = 0; r < 4; r++) {
        int row = qbase + mt * 16 + quad * 4 + r;
        out[((size_t)b * Sc + row) * Dc + col] = o[mt][dt][r] * inv[r];
      }
    }
  }
}

// ---------------------------------------------------------------------------
extern "C" void kernel_launch(void* const* d_in, const int* in_sizes, int n_in,
                              void* d_out, int out_size, void* d_ws,
                              size_t ws_size, hipStream_t stream) {
  (void)in_sizes; (void)n_in; (void)out_size; (void)ws_size;
  const float* hidden = (const float*)d_in[0];
  const float* mask   = (const float*)d_in[1];
  const float* Wq     = (const float*)d_in[2];
  const float* bq     = (const float*)d_in[3];
  const float* Wk     = (const float*)d_in[4];
  const float* bk     = (const float*)d_in[5];
  const float* Wv     = (const float*)d_in[6];
  const float* bv     = (const float*)d_in[7];
  float* out = (float*)d_out;

  uint8_t* w = (uint8_t*)d_ws;
  f16* Wt   = (f16*)(w);                               //  6 MB
  f16* X16  = (f16*)(w + (size_t)6 * 1024 * 1024);     // 16 MB
  f16* Q16  = (f16*)(w + (size_t)22 * 1024 * 1024);    // 16 MB (pre-scaled)
  f16* K16  = (f16*)(w + (size_t)38 * 1024 * 1024);    // 16 MB
  f16* Vt16 = (f16*)(w + (size_t)54 * 1024 * 1024);    // 16 MB, transposed

  cast_w_kernel<<<dim3(16, 16, 3), 256, 0, stream>>>(Wq, Wk, Wv, Wt);
  cast_x_kernel<<<4096, 256, 0, stream>>>(hidden, X16);
  qkv_gemm_kernel<<<dim3(1536), 256, 0, stream>>>(X16, Wt, bq, bk, bv,
                                                  Q16, K16, Vt16);
  flash_kernel<<<dim3(512), 256, 0, stream>>>(Q16, K16, Vt16, mask, out);
}

// Round 9
// 267.964 us; speedup vs baseline: 1.0224x; 1.0224x over previous
//
#include <hip/hip_runtime.h>
#include <hip/hip_bf16.h>
#include <cstdint>

typedef _Float16 f16;
typedef f16 f16x8 __attribute__((ext_vector_type(8)));
typedef f16 f16x4 __attribute__((ext_vector_type(4)));
typedef float f32x4 __attribute__((ext_vector_type(4)));

#define MFMA16(a, b, c) __builtin_amdgcn_mfma_f32_16x16x32_f16((a), (b), (c), 0, 0, 0)

constexpr int Bc = 4, Sc = 2048, Dc = 1024, Hc = 16, DHc = 64;

typedef __attribute__((address_space(1))) const uint32_t gbl_u32;
typedef __attribute__((address_space(3))) uint32_t lds_u32;
__device__ __forceinline__ void gld_lds16(const void* g, void* l) {
  __builtin_amdgcn_global_load_lds((gbl_u32*)g, (lds_u32*)l, 16, 0, 0);
}

// ---------------------------------------------------------------------------
// Kernel 1: cast+transpose weights: W fp32 [K=1024][N=1024] -> Wt f16 [z][N][K]
// (viewed by the GEMM as one [3072][1024] B^T matrix)
// ---------------------------------------------------------------------------
__global__ __launch_bounds__(256) void cast_w_kernel(
    const float* __restrict__ Wq, const float* __restrict__ Wk,
    const float* __restrict__ Wv, f16* __restrict__ Wt) {
  __shared__ __align__(16) f16 T[64][66];
  const int z = blockIdx.z;
  const float* W = (z == 0) ? Wq : (z == 1) ? Wk : Wv;
  const int n0 = blockIdx.x * 64, k0 = blockIdx.y * 64;
  const int t = threadIdx.x;
#pragma unroll
  for (int p = 0; p < 4; p++) {
    int idx = t + p * 256;
    int r = idx >> 4, c = idx & 15;
    float4 v = *(const float4*)(W + (size_t)(k0 + r) * Dc + n0 + c * 4);
    T[r][c * 4 + 0] = (f16)v.x;
    T[r][c * 4 + 1] = (f16)v.y;
    T[r][c * 4 + 2] = (f16)v.z;
    T[r][c * 4 + 3] = (f16)v.w;
  }
  __syncthreads();
#pragma unroll
  for (int p = 0; p < 2; p++) {
    int idx = t + p * 256;
    int n = idx >> 3, c = idx & 7;
    f16x8 tmp;
#pragma unroll
    for (int j = 0; j < 8; j++) tmp[j] = T[c * 8 + j][n];
    *(f16x8*)(Wt + ((size_t)z * Dc + n0 + n) * Dc + k0 + c * 8) = tmp;
  }
}

// ---------------------------------------------------------------------------
// Kernel 1b: cast X fp32 -> f16.
// ---------------------------------------------------------------------------
__global__ __launch_bounds__(256) void cast_x_kernel(const float* __restrict__ X,
                                                     f16* __restrict__ X16) {
  size_t i = ((size_t)blockIdx.x * 256 + threadIdx.x) * 8;
  float4 a = *(const float4*)(X + i);
  float4 b = *(const float4*)(X + i + 4);
  f16x8 h;
  h[0] = (f16)a.x; h[1] = (f16)a.y; h[2] = (f16)a.z; h[3] = (f16)a.w;
  h[4] = (f16)b.x; h[5] = (f16)b.y; h[6] = (f16)b.z; h[7] = (f16)b.w;
  *(f16x8*)(X16 + i) = h;
}

// ---------------------------------------------------------------------------
// Kernel 2 (R7): R2's fused QKV GEMM (BK=32 m97 structure, measured-best
// GEMM segment) + ONE delta: z<2 computes C^T (swapped MFMA operands, same
// LDS reads) so the epilogue packs f16x4 along d — 16x8B stores/thread
// instead of 64x2B scalar. z==2 unchanged (packs along s into Vt).
// XCD-chunked swizzle: lin&7 = XCD, m-tile innermost.
// Q pre-scaled by 0.125*log2(e) for the flash exp2 path.
// ---------------------------------------------------------------------------
__global__ __launch_bounds__(256) void qkv_gemm_kernel(
    const f16* __restrict__ X16, const f16* __restrict__ Wt,
    const float* __restrict__ bq, const float* __restrict__ bk,
    const float* __restrict__ bv, f16* __restrict__ Qo, f16* __restrict__ Ko,
    f16* __restrict__ Vo) {
  const int lin = blockIdx.x;               // 1536 blocks
  const int xcd = lin & 7, jj = lin >> 3;   // jj in [0,192)
  const int bn = jj >> 3;                   // 0..23 (n-tile over fused N=3072)
  const int bm = (xcd << 3) | (jj & 7);     // 0..63 (m-tile, innermost)
  const int z = bn >> 3;
  const int n0 = (bn & 7) * 128;            // col base within this z
  const int m0 = bm * 128;
  const f16* W = Wt + (size_t)bn * 128 * Dc;
  const float* bias = (z == 0) ? bq : (z == 1) ? bk : bv;
  const bool zqk = (z != 2);

  __shared__ __align__(16) f16 Xs[128 * 32];
  __shared__ __align__(16) f16 Ws[128 * 32];

  const int t = threadIdx.x;
  const int wave = t >> 6, lane = t & 63;
  const int l16 = lane & 15, quad = lane >> 4;
  const int wm = (wave >> 1) * 64, wn = (wave & 1) * 64;

  f32x4 acc[4][4];  // z<2: [nt][mt] (C^T); z==2: [mt][nt]
#pragma unroll
  for (int i = 0; i < 4; i++)
#pragma unroll
    for (int j = 0; j < 4; j++) acc[i][j] = (f32x4){0.f, 0.f, 0.f, 0.f};

  for (int k0 = 0; k0 < Dc; k0 += 32) {
#pragma unroll
    for (int p = 0; p < 2; p++) {
      int cb = p * 256 + wave * 64;
      int chunk = cb + lane;
      int row = chunk >> 2, c8 = (chunk & 3) * 8;
      gld_lds16(X16 + (size_t)(m0 + row) * Dc + k0 + c8, (f16*)Xs + (size_t)cb * 8);
      gld_lds16(W + (size_t)row * Dc + k0 + c8, (f16*)Ws + (size_t)cb * 8);
    }
    __syncthreads();

    f16x8 aF[4], bF[4];
#pragma unroll
    for (int mt = 0; mt < 4; mt++)
      aF[mt] = *(const f16x8*)(&Xs[(wm + mt * 16 + l16) * 32 + quad * 8]);
#pragma unroll
    for (int nt = 0; nt < 4; nt++)
      bF[nt] = *(const f16x8*)(&Ws[(wn + nt * 16 + l16) * 32 + quad * 8]);
    if (zqk) {
#pragma unroll
      for (int nt = 0; nt < 4; nt++)
#pragma unroll
        for (int mt = 0; mt < 4; mt++)
          acc[nt][mt] = MFMA16(bF[nt], aF[mt], acc[nt][mt]);
    } else {
#pragma unroll
      for (int mt = 0; mt < 4; mt++)
#pragma unroll
        for (int nt = 0; nt < 4; nt++)
          acc[mt][nt] = MFMA16(aF[mt], bF[nt], acc[mt][nt]);
    }
    __syncthreads();
  }

  if (zqk) {
    // C^T epilogue: row(quad*4+r) = d, col(l16) = s -> f16x4 pack along d
    f16* O = (z == 0) ? Qo : Ko;
    const float sc = (z == 0) ? 0.18033688011112042f : 1.0f;  // Q: 0.125*log2e
    const int h = (n0 + wn) >> 6;
#pragma unroll
    for (int nt = 0; nt < 4; nt++) {
      int cb = n0 + wn + nt * 16 + quad * 4;
      float4 bv4 = *(const float4*)(bias + cb);
      int d0 = nt * 16 + quad * 4;
#pragma unroll
      for (int mt = 0; mt < 4; mt++) {
        int m = m0 + wm + mt * 16 + l16;
        int b = m >> 11, s = m & 2047;
        f16x4 pk;
        pk[0] = (f16)((acc[nt][mt][0] + bv4.x) * sc);
        pk[1] = (f16)((acc[nt][mt][1] + bv4.y) * sc);
        pk[2] = (f16)((acc[nt][mt][2] + bv4.z) * sc);
        pk[3] = (f16)((acc[nt][mt][3] + bv4.w) * sc);
        *(f16x4*)(O + (((size_t)(b * Hc + h)) * Sc + s) * DHc + d0) = pk;
      }
    }
  } else {
    // V epilogue: r runs along s -> f16x4 pack along s into Vt [bh][d][s]
#pragma unroll
    for (int nt = 0; nt < 4; nt++) {
      int col = n0 + wn + nt * 16 + l16;
      float bval = bias[col];
      int h = col >> 6, d = col & 63;
#pragma unroll
      for (int mt = 0; mt < 4; mt++) {
        int m = m0 + wm + mt * 16 + quad * 4;
        int b = m >> 11, sbase = m & 2047;
        f16x4 pk;
#pragma unroll
        for (int r = 0; r < 4; r++) pk[r] = (f16)(acc[mt][nt][r] + bval);
        *(f16x4*)(Vo + (((size_t)(b * Hc + h)) * DHc + d) * Sc + sbase) = pk;
      }
    }
  }
}

// ---------------------------------------------------------------------------
// Kernel 3 (R7): flash attention — byte-for-byte revert to the R3 version
// (measured 98.4 us): 32 queries/wave, 1024 blocks = 4 blocks/CU (the R4
// 64q/wave variant halved resident waves -> occupancy 10.9% -> 115 us).
// Register-resident P via KEY-PERMUTED K staging; XCD-chunked bh; mask in
// LDS pre-scaled by log2(e); l row-sums on the MFMA pipe.
// ---------------------------------------------------------------------------
__global__ __launch_bounds__(256) void flash_kernel(
    const f16* __restrict__ Q, const f16* __restrict__ K,
    const f16* __restrict__ Vt, const float* __restrict__ mask,
    float* __restrict__ out) {
  const int lin = blockIdx.x;               // 1024 blocks
  const int xcd = lin & 7, jj = lin >> 3;   // jj in [0,128)
  const int bh = (xcd << 3) | (jj & 7);     // 0..63 (inner: bh cycles fastest)
  const int qt = jj >> 3;                   // 0..15
  const int b = bh >> 4, h = bh & 15;
  const int t = threadIdx.x;
  const int wave = t >> 6, lane = t & 63;
  const int l16 = lane & 15, quad = lane >> 4;
  const int qbase = qt * 128 + wave * 32;

  __shared__ __align__(16) f16 Ks[2][4096];  // [buf][half*2048+row*32+oct*8]
  __shared__ __align__(16) f16 Vs[2][4096];  // [buf][kh*2048+dh*32+oct*8]
  __shared__ __align__(16) float Ms[2048];   // mask row * log2(e)

  const f16* Kb = K + (size_t)bh * Sc * DHc;
  const f16* Vb = Vt + (size_t)bh * DHc * Sc;

  constexpr float L2E = 1.44269504088896340736f;

  // swizzled b128 read position (same for K and V frags)
  const int qsw8 = (quad ^ ((l16 >> 1) & 3)) * 8;

  // octet i -> half=i>>8, row=(i>>2)&63, pos q8=i&3 holds global octet
  // q8^((row>>1)&3). K rows are PERMUTED: staged row k holds global key
  // phys(k): [n1 n0 q1 q0 r1 r0] -> [n1 q1 q0 n0 r1 r0].
  const f16* kp[2];
  const f16* vp[2];
  int ldsOff[2];
#pragma unroll
  for (int p = 0; p < 2; p++) {
    int cb = p * 256 + wave * 64;  // wave-uniform octet base
    int i = cb + lane;
    int half = i >> 8, row = (i >> 2) & 63, q8 = i & 3;
    int q8g = q8 ^ ((row >> 1) & 3);
    int g = (row & 32) | ((row & 12) << 1) | ((row & 16) >> 2) | (row & 3);
    kp[p] = Kb + (size_t)g * DHc + half * 32 + q8g * 8;
    vp[p] = Vb + (size_t)row * Sc + half * 32 + q8g * 8;
    ldsOff[p] = cb * 8;
  }
  auto stage = [&](int buf) {
#pragma unroll
    for (int p = 0; p < 2; p++) {
      gld_lds16(kp[p], (f16*)Ks + buf * 4096 + ldsOff[p]);
      gld_lds16(vp[p], (f16*)Vs + buf * 4096 + ldsOff[p]);
      kp[p] += 64 * DHc;  // next chunk: 64 more key rows
      vp[p] += 64;        // next chunk: 64 more key columns
    }
  };

  // Q B-frags for 2 m-tiles; pre-scaled by 0.125*log2(e) in the GEMM epilogue.
  f16x8 qa[2][2];
#pragma unroll
  for (int mt = 0; mt < 2; mt++) {
    const f16* qb = Q + ((size_t)bh * Sc + qbase + mt * 16 + l16) * DHc;
    qa[mt][0] = *(const f16x8*)(qb + quad * 8);
    qa[mt][1] = *(const f16x8*)(qb + 32 + quad * 8);
  }

  // all-ones B-frag for the l row-sum MFMAs
  f16x8 ones;
#pragma unroll
  for (int j = 0; j < 8; j++) ones[j] = (f16)1.0f;

  // prologue: stage chunk 0; fill mask LDS (pre-scaled into exp2 domain)
  stage(0);
  {
    const float* mrow = mask + (size_t)b * Sc + t * 8;
    float4 a0 = *(const float4*)(mrow);
    float4 a1 = *(const float4*)(mrow + 4);
    *(f32x4*)(&Ms[t * 8]) = (f32x4){a0.x * L2E, a0.y * L2E, a0.z * L2E, a0.w * L2E};
    *(f32x4*)(&Ms[t * 8 + 4]) = (f32x4){a1.x * L2E, a1.y * L2E, a1.z * L2E, a1.w * L2E};
  }
  __syncthreads();

  f32x4 lacc[2];
  f32x4 o[2][4];
#pragma unroll
  for (int mt = 0; mt < 2; mt++) {
    lacc[mt] = (f32x4){0.f, 0.f, 0.f, 0.f};
#pragma unroll
    for (int dt = 0; dt < 4; dt++) o[mt][dt] = (f32x4){0.f, 0.f, 0.f, 0.f};
  }

  for (int c = 0; c < 32; c++) {
    const int buf = c & 1;
    if (c < 31) stage(buf ^ 1);

    // mask C-init from LDS (broadcast within quads, conflict-free across)
    const int mb = c * 64 + quad * 8;
    f32x4 minit[4];
    minit[0] = *(const f32x4*)(&Ms[mb + 0]);
    minit[1] = *(const f32x4*)(&Ms[mb + 4]);
    minit[2] = *(const f32x4*)(&Ms[mb + 32]);
    minit[3] = *(const f32x4*)(&Ms[mb + 36]);

    // K A-frags (staged/permuted rows), swizzled b128 positions
    f16x8 ka[4][2];
#pragma unroll
    for (int nt = 0; nt < 4; nt++) {
      int rb = (nt * 16 + l16) * 32 + qsw8;
      ka[nt][0] = *(const f16x8*)(&Ks[buf][rb]);
      ka[nt][1] = *(const f16x8*)(&Ks[buf][2048 + rb]);
    }

    // ---- QK both m-tiles: S^T = K*Q^T + mask (C-init), log2 domain ----
    f32x4 s0[4], s1[4];
#pragma unroll
    for (int nt = 0; nt < 4; nt++) {
      f32x4 a = minit[nt];
      a = MFMA16(ka[nt][0], qa[0][0], a);
      a = MFMA16(ka[nt][1], qa[0][1], a);
      s0[nt] = a;
      f32x4 a2 = minit[nt];
      a2 = MFMA16(ka[nt][0], qa[1][0], a2);
      a2 = MFMA16(ka[nt][1], qa[1][1], a2);
      s1[nt] = a2;
    }

    // ---- exp2 + pack: under the key permutation this IS the A-layout ----
    f16x8 pa[2][2];  // [mt][blk]
#pragma unroll
    for (int blk = 0; blk < 2; blk++) {
      f16x8 p0, p1;
#pragma unroll
      for (int half = 0; half < 2; half++) {
        int nt = blk * 2 + half;
#pragma unroll
        for (int r = 0; r < 4; r++) {
          p0[half * 4 + r] = (f16)__builtin_amdgcn_exp2f(s0[nt][r]);
          p1[half * 4 + r] = (f16)__builtin_amdgcn_exp2f(s1[nt][r]);
        }
      }
      pa[0][blk] = p0;
      pa[1][blk] = p1;
    }

    // ---- l row-sums on the MFMA pipe ----
    lacc[0] = MFMA16(pa[0][0], ones, lacc[0]);
    lacc[0] = MFMA16(pa[0][1], ones, lacc[0]);
    lacc[1] = MFMA16(pa[1][0], ones, lacc[1]);
    lacc[1] = MFMA16(pa[1][1], ones, lacc[1]);

    // ---- PV: 16x16x32, V b128 frags shared by both m-tiles ----
#pragma unroll
    for (int dt = 0; dt < 4; dt++) {
      int rb = (dt * 16 + l16) * 32 + qsw8;
      f16x8 v0 = *(const f16x8*)(&Vs[buf][rb]);
      f16x8 v1 = *(const f16x8*)(&Vs[buf][2048 + rb]);
      o[0][dt] = MFMA16(pa[0][0], v0, o[0][dt]);
      o[0][dt] = MFMA16(pa[0][1], v1, o[0][dt]);
      o[1][dt] = MFMA16(pa[1][0], v0, o[1][dt]);
      o[1][dt] = MFMA16(pa[1][1], v1, o[1][dt]);
    }

    __syncthreads();
  }

  // ---- epilogue: lacc D-layout rows (quad*4+r) == o rows; no shuffles ----
#pragma unroll
  for (int mt = 0; mt < 2; mt++) {
    float inv[4];
#pragma unroll
    for (int r = 0; r < 4; r++) inv[r] = 1.0f / lacc[mt][r];
#pragma unroll
    for (int dt = 0; dt < 4; dt++) {
      int col = h * 64 + dt * 16 + l16;
#pragma unroll
      for (int r = 0; r < 4; r++) {
        int row = qbase + mt * 16 + quad * 4 + r;
        out[((size_t)b * Sc + row) * Dc + col] = o[mt][dt][r] * inv[r];
      }
    }
  }
}

// ---------------------------------------------------------------------------
extern "C" void kernel_launch(void* const* d_in, const int* in_sizes, int n_in,
                              void* d_out, int out_size, void* d_ws,
                              size_t ws_size, hipStream_t stream) {
  (void)in_sizes; (void)n_in; (void)out_size; (void)ws_size;
  const float* hidden = (const float*)d_in[0];
  const float* mask   = (const float*)d_in[1];
  const float* Wq     = (const float*)d_in[2];
  const float* bq     = (const float*)d_in[3];
  const float* Wk     = (const float*)d_in[4];
  const float* bk     = (const float*)d_in[5];
  const float* Wv     = (const float*)d_in[6];
  const float* bv     = (const float*)d_in[7];
  float* out = (float*)d_out;

  uint8_t* w = (uint8_t*)d_ws;
  f16* Wt   = (f16*)(w);                               //  6 MB
  f16* X16  = (f16*)(w + (size_t)6 * 1024 * 1024);     // 16 MB
  f16* Q16  = (f16*)(w + (size_t)22 * 1024 * 1024);    // 16 MB (pre-scaled)
  f16* K16  = (f16*)(w + (size_t)38 * 1024 * 1024);    // 16 MB
  f16* Vt16 = (f16*)(w + (size_t)54 * 1024 * 1024);    // 16 MB, transposed

  cast_w_kernel<<<dim3(16, 16, 3), 256, 0, stream>>>(Wq, Wk, Wv, Wt);
  cast_x_kernel<<<4096, 256, 0, stream>>>(hidden, X16);
  qkv_gemm_kernel<<<dim3(1536), 256, 0, stream>>>(X16, Wt, bq, bk, bv,
                                                  Q16, K16, Vt16);
  flash_kernel<<<dim3(1024), 256, 0, stream>>>(Q16, K16, Vt16, mask, out);
}

// Round 10
// 253.672 us; speedup vs baseline: 1.0800x; 1.0563x over previous
//
#include <hip/hip_runtime.h>
#include <hip/hip_bf16.h>
#include <cstdint>

typedef _Float16 f16;
typedef f16 f16x8 __attribute__((ext_vector_type(8)));
typedef f16 f16x4 __attribute__((ext_vector_type(4)));
typedef float f32x4 __attribute__((ext_vector_type(4)));

#define MFMA16(a, b, c) __builtin_amdgcn_mfma_f32_16x16x32_f16((a), (b), (c), 0, 0, 0)

constexpr int Bc = 4, Sc = 2048, Dc = 1024, Hc = 16, DHc = 64;

typedef __attribute__((address_space(1))) const uint32_t gbl_u32;
typedef __attribute__((address_space(3))) uint32_t lds_u32;
__device__ __forceinline__ void gld_lds16(const void* g, void* l) {
  __builtin_amdgcn_global_load_lds((gbl_u32*)g, (lds_u32*)l, 16, 0, 0);
}

// ---------------------------------------------------------------------------
// Kernel 1: cast+transpose weights: W fp32 [K=1024][N=1024] -> Wt f16 [z][N][K]
// (viewed by the GEMM as one [3072][1024] B^T matrix)
// ---------------------------------------------------------------------------
__global__ __launch_bounds__(256) void cast_w_kernel(
    const float* __restrict__ Wq, const float* __restrict__ Wk,
    const float* __restrict__ Wv, f16* __restrict__ Wt) {
  __shared__ __align__(16) f16 T[64][66];
  const int z = blockIdx.z;
  const float* W = (z == 0) ? Wq : (z == 1) ? Wk : Wv;
  const int n0 = blockIdx.x * 64, k0 = blockIdx.y * 64;
  const int t = threadIdx.x;
#pragma unroll
  for (int p = 0; p < 4; p++) {
    int idx = t + p * 256;
    int r = idx >> 4, c = idx & 15;
    float4 v = *(const float4*)(W + (size_t)(k0 + r) * Dc + n0 + c * 4);
    T[r][c * 4 + 0] = (f16)v.x;
    T[r][c * 4 + 1] = (f16)v.y;
    T[r][c * 4 + 2] = (f16)v.z;
    T[r][c * 4 + 3] = (f16)v.w;
  }
  __syncthreads();
#pragma unroll
  for (int p = 0; p < 2; p++) {
    int idx = t + p * 256;
    int n = idx >> 3, c = idx & 7;
    f16x8 tmp;
#pragma unroll
    for (int j = 0; j < 8; j++) tmp[j] = T[c * 8 + j][n];
    *(f16x8*)(Wt + ((size_t)z * Dc + n0 + n) * Dc + k0 + c * 8) = tmp;
  }
}

// ---------------------------------------------------------------------------
// Kernel 1b: cast X fp32 -> f16.
// ---------------------------------------------------------------------------
__global__ __launch_bounds__(256) void cast_x_kernel(const float* __restrict__ X,
                                                     f16* __restrict__ X16) {
  size_t i = ((size_t)blockIdx.x * 256 + threadIdx.x) * 8;
  float4 a = *(const float4*)(X + i);
  float4 b = *(const float4*)(X + i + 4);
  f16x8 h;
  h[0] = (f16)a.x; h[1] = (f16)a.y; h[2] = (f16)a.z; h[3] = (f16)a.w;
  h[4] = (f16)b.x; h[5] = (f16)b.y; h[6] = (f16)b.z; h[7] = (f16)b.w;
  *(f16x8*)(X16 + i) = h;
}

// ---------------------------------------------------------------------------
// Kernel 2 (R10): byte-exact revert to R2's fused QKV GEMM (measured rest
// segment 149.0 us; R9's packed-C^T Q/K epilogue cost +21 us — scattered
// 8B stores at 128B stride touch 64 lines/instr vs ~4 for the scalar
// quad-contiguous pattern. Store COALESCING beats store COUNT here.)
// m97 structure: BK=32, gld_lds16 staging, 2 barriers/step.
// XCD-chunked swizzle: lin&7 = XCD, m-tile innermost.
// Q pre-scaled by 0.125*log2(e) for the flash exp2 path.
// ---------------------------------------------------------------------------
__global__ __launch_bounds__(256) void qkv_gemm_kernel(
    const f16* __restrict__ X16, const f16* __restrict__ Wt,
    const float* __restrict__ bq, const float* __restrict__ bk,
    const float* __restrict__ bv, f16* __restrict__ Qo, f16* __restrict__ Ko,
    f16* __restrict__ Vo) {
  const int lin = blockIdx.x;               // 1536 blocks
  const int xcd = lin & 7, jj = lin >> 3;   // jj in [0,192)
  const int bn = jj >> 3;                   // 0..23 (n-tile over fused N=3072)
  const int bm = (xcd << 3) | (jj & 7);     // 0..63 (m-tile; inner index)
  const int z = bn >> 3;
  const int n0 = (bn & 7) * 128;            // col base within this z
  const int m0 = bm * 128;
  const f16* W = Wt + (size_t)bn * 128 * Dc;  // rows [bn*128, bn*128+128)
  const float* bias = (z == 0) ? bq : (z == 1) ? bk : bv;

  __shared__ __align__(16) f16 Xs[128 * 32];
  __shared__ __align__(16) f16 Ws[128 * 32];

  const int t = threadIdx.x;
  const int wave = t >> 6, lane = t & 63;
  const int l16 = lane & 15, quad = lane >> 4;
  const int wm = (wave >> 1) * 64, wn = (wave & 1) * 64;

  f32x4 acc[4][4];
#pragma unroll
  for (int i = 0; i < 4; i++)
#pragma unroll
    for (int j = 0; j < 4; j++) acc[i][j] = (f32x4){0.f, 0.f, 0.f, 0.f};

  for (int k0 = 0; k0 < Dc; k0 += 32) {
#pragma unroll
    for (int p = 0; p < 2; p++) {
      int cb = p * 256 + wave * 64;
      int chunk = cb + lane;
      int row = chunk >> 2, c8 = (chunk & 3) * 8;
      gld_lds16(X16 + (size_t)(m0 + row) * Dc + k0 + c8, (f16*)Xs + (size_t)cb * 8);
      gld_lds16(W + (size_t)row * Dc + k0 + c8, (f16*)Ws + (size_t)cb * 8);
    }
    __syncthreads();

    f16x8 aF[4], bF[4];
#pragma unroll
    for (int mt = 0; mt < 4; mt++)
      aF[mt] = *(const f16x8*)(&Xs[(wm + mt * 16 + l16) * 32 + quad * 8]);
#pragma unroll
    for (int nt = 0; nt < 4; nt++)
      bF[nt] = *(const f16x8*)(&Ws[(wn + nt * 16 + l16) * 32 + quad * 8]);
#pragma unroll
    for (int mt = 0; mt < 4; mt++)
#pragma unroll
      for (int nt = 0; nt < 4; nt++)
        acc[mt][nt] = MFMA16(aF[mt], bF[nt], acc[mt][nt]);
    __syncthreads();
  }

#pragma unroll
  for (int nt = 0; nt < 4; nt++) {
    int col = n0 + wn + nt * 16 + l16;   // within-z column, 0..1023
    float bval = bias[col];
    int h = col >> 6, d = col & 63;
    if (z == 2) {
#pragma unroll
      for (int mt = 0; mt < 4; mt++) {
        int m = m0 + wm + mt * 16 + quad * 4;
        int b = m >> 11, sbase = m & 2047;
        f16x4 pk;
#pragma unroll
        for (int r = 0; r < 4; r++) pk[r] = (f16)(acc[mt][nt][r] + bval);
        *(f16x4*)(Vo + (((size_t)(b * Hc + h)) * DHc + d) * Sc + sbase) = pk;
      }
    } else {
      // z==0 (Q): fold softmax scale 1/sqrt(64)=0.125 AND log2(e) so flash
      // uses exp2 directly.  z==1 (K): 1.0.
      const float sc = (z == 0) ? 0.18033688011112042f : 1.0f;
      f16* O = (z == 0) ? Qo : Ko;
#pragma unroll
      for (int mt = 0; mt < 4; mt++) {
#pragma unroll
        for (int r = 0; r < 4; r++) {
          int m = m0 + wm + mt * 16 + quad * 4 + r;
          int b = m >> 11, s = m & 2047;
          O[(((size_t)(b * Hc + h)) * Sc + s) * DHc + d] =
              (f16)((acc[mt][nt][r] + bval) * sc);
        }
      }
    }
  }
}

// ---------------------------------------------------------------------------
// Kernel 3 (R10): flash attention — unchanged from R3/R9 (measured 98.1 us):
// 32 queries/wave, 1024 blocks = 4/CU, XCD-chunked bh, register-resident P
// via KEY-PERMUTED K staging, mask in LDS pre-scaled by log2(e), l row-sums
// on the MFMA pipe.
// ---------------------------------------------------------------------------
__global__ __launch_bounds__(256) void flash_kernel(
    const f16* __restrict__ Q, const f16* __restrict__ K,
    const f16* __restrict__ Vt, const float* __restrict__ mask,
    float* __restrict__ out) {
  const int lin = blockIdx.x;               // 1024 blocks
  const int xcd = lin & 7, jj = lin >> 3;   // jj in [0,128)
  const int bh = (xcd << 3) | (jj & 7);     // 0..63 (inner: bh cycles fastest)
  const int qt = jj >> 3;                   // 0..15
  const int b = bh >> 4, h = bh & 15;
  const int t = threadIdx.x;
  const int wave = t >> 6, lane = t & 63;
  const int l16 = lane & 15, quad = lane >> 4;
  const int qbase = qt * 128 + wave * 32;

  __shared__ __align__(16) f16 Ks[2][4096];  // [buf][half*2048+row*32+oct*8]
  __shared__ __align__(16) f16 Vs[2][4096];  // [buf][kh*2048+dh*32+oct*8]
  __shared__ __align__(16) float Ms[2048];   // mask row * log2(e)

  const f16* Kb = K + (size_t)bh * Sc * DHc;
  const f16* Vb = Vt + (size_t)bh * DHc * Sc;

  constexpr float L2E = 1.44269504088896340736f;

  // swizzled b128 read position (same for K and V frags)
  const int qsw8 = (quad ^ ((l16 >> 1) & 3)) * 8;

  // octet i -> half=i>>8, row=(i>>2)&63, pos q8=i&3 holds global octet
  // q8^((row>>1)&3). K rows are PERMUTED: staged row k holds global key
  // phys(k): [n1 n0 q1 q0 r1 r0] -> [n1 q1 q0 n0 r1 r0].
  const f16* kp[2];
  const f16* vp[2];
  int ldsOff[2];
#pragma unroll
  for (int p = 0; p < 2; p++) {
    int cb = p * 256 + wave * 64;  // wave-uniform octet base
    int i = cb + lane;
    int half = i >> 8, row = (i >> 2) & 63, q8 = i & 3;
    int q8g = q8 ^ ((row >> 1) & 3);
    int g = (row & 32) | ((row & 12) << 1) | ((row & 16) >> 2) | (row & 3);
    kp[p] = Kb + (size_t)g * DHc + half * 32 + q8g * 8;
    vp[p] = Vb + (size_t)row * Sc + half * 32 + q8g * 8;
    ldsOff[p] = cb * 8;
  }
  auto stage = [&](int buf) {
#pragma unroll
    for (int p = 0; p < 2; p++) {
      gld_lds16(kp[p], (f16*)Ks + buf * 4096 + ldsOff[p]);
      gld_lds16(vp[p], (f16*)Vs + buf * 4096 + ldsOff[p]);
      kp[p] += 64 * DHc;  // next chunk: 64 more key rows
      vp[p] += 64;        // next chunk: 64 more key columns
    }
  };

  // Q B-frags for 2 m-tiles; pre-scaled by 0.125*log2(e) in the GEMM epilogue.
  f16x8 qa[2][2];
#pragma unroll
  for (int mt = 0; mt < 2; mt++) {
    const f16* qb = Q + ((size_t)bh * Sc + qbase + mt * 16 + l16) * DHc;
    qa[mt][0] = *(const f16x8*)(qb + quad * 8);
    qa[mt][1] = *(const f16x8*)(qb + 32 + quad * 8);
  }

  // all-ones B-frag for the l row-sum MFMAs
  f16x8 ones;
#pragma unroll
  for (int j = 0; j < 8; j++) ones[j] = (f16)1.0f;

  // prologue: stage chunk 0; fill mask LDS (pre-scaled into exp2 domain)
  stage(0);
  {
    const float* mrow = mask + (size_t)b * Sc + t * 8;
    float4 a0 = *(const float4*)(mrow);
    float4 a1 = *(const float4*)(mrow + 4);
    *(f32x4*)(&Ms[t * 8]) = (f32x4){a0.x * L2E, a0.y * L2E, a0.z * L2E, a0.w * L2E};
    *(f32x4*)(&Ms[t * 8 + 4]) = (f32x4){a1.x * L2E, a1.y * L2E, a1.z * L2E, a1.w * L2E};
  }
  __syncthreads();

  f32x4 lacc[2];
  f32x4 o[2][4];
#pragma unroll
  for (int mt = 0; mt < 2; mt++) {
    lacc[mt] = (f32x4){0.f, 0.f, 0.f, 0.f};
#pragma unroll
    for (int dt = 0; dt < 4; dt++) o[mt][dt] = (f32x4){0.f, 0.f, 0.f, 0.f};
  }

  for (int c = 0; c < 32; c++) {
    const int buf = c & 1;
    if (c < 31) stage(buf ^ 1);

    // mask C-init from LDS (broadcast within quads, conflict-free across)
    const int mb = c * 64 + quad * 8;
    f32x4 minit[4];
    minit[0] = *(const f32x4*)(&Ms[mb + 0]);
    minit[1] = *(const f32x4*)(&Ms[mb + 4]);
    minit[2] = *(const f32x4*)(&Ms[mb + 32]);
    minit[3] = *(const f32x4*)(&Ms[mb + 36]);

    // K A-frags (staged/permuted rows), swizzled b128 positions
    f16x8 ka[4][2];
#pragma unroll
    for (int nt = 0; nt < 4; nt++) {
      int rb = (nt * 16 + l16) * 32 + qsw8;
      ka[nt][0] = *(const f16x8*)(&Ks[buf][rb]);
      ka[nt][1] = *(const f16x8*)(&Ks[buf][2048 + rb]);
    }

    // ---- QK both m-tiles: S^T = K*Q^T + mask (C-init), log2 domain ----
    f32x4 s0[4], s1[4];
#pragma unroll
    for (int nt = 0; nt < 4; nt++) {
      f32x4 a = minit[nt];
      a = MFMA16(ka[nt][0], qa[0][0], a);
      a = MFMA16(ka[nt][1], qa[0][1], a);
      s0[nt] = a;
      f32x4 a2 = minit[nt];
      a2 = MFMA16(ka[nt][0], qa[1][0], a2);
      a2 = MFMA16(ka[nt][1], qa[1][1], a2);
      s1[nt] = a2;
    }

    // ---- exp2 + pack: under the key permutation this IS the A-layout ----
    f16x8 pa[2][2];  // [mt][blk]
#pragma unroll
    for (int blk = 0; blk < 2; blk++) {
      f16x8 p0, p1;
#pragma unroll
      for (int half = 0; half < 2; half++) {
        int nt = blk * 2 + half;
#pragma unroll
        for (int r = 0; r < 4; r++) {
          p0[half * 4 + r] = (f16)__builtin_amdgcn_exp2f(s0[nt][r]);
          p1[half * 4 + r] = (f16)__builtin_amdgcn_exp2f(s1[nt][r]);
        }
      }
      pa[0][blk] = p0;
      pa[1][blk] = p1;
    }

    // ---- l row-sums on the MFMA pipe ----
    lacc[0] = MFMA16(pa[0][0], ones, lacc[0]);
    lacc[0] = MFMA16(pa[0][1], ones, lacc[0]);
    lacc[1] = MFMA16(pa[1][0], ones, lacc[1]);
    lacc[1] = MFMA16(pa[1][1], ones, lacc[1]);

    // ---- PV: 16x16x32, V b128 frags shared by both m-tiles ----
#pragma unroll
    for (int dt = 0; dt < 4; dt++) {
      int rb = (dt * 16 + l16) * 32 + qsw8;
      f16x8 v0 = *(const f16x8*)(&Vs[buf][rb]);
      f16x8 v1 = *(const f16x8*)(&Vs[buf][2048 + rb]);
      o[0][dt] = MFMA16(pa[0][0], v0, o[0][dt]);
      o[0][dt] = MFMA16(pa[0][1], v1, o[0][dt]);
      o[1][dt] = MFMA16(pa[1][0], v0, o[1][dt]);
      o[1][dt] = MFMA16(pa[1][1], v1, o[1][dt]);
    }

    __syncthreads();
  }

  // ---- epilogue: lacc D-layout rows (quad*4+r) == o rows; no shuffles ----
#pragma unroll
  for (int mt = 0; mt < 2; mt++) {
    float inv[4];
#pragma unroll
    for (int r = 0; r < 4; r++) inv[r] = 1.0f / lacc[mt][r];
#pragma unroll
    for (int dt = 0; dt < 4; dt++) {
      int col = h * 64 + dt * 16 + l16;
#pragma unroll
      for (int r = 0; r < 4; r++) {
        int row = qbase + mt * 16 + quad * 4 + r;
        out[((size_t)b * Sc + row) * Dc + col] = o[mt][dt][r] * inv[r];
      }
    }
  }
}

// ---------------------------------------------------------------------------
extern "C" void kernel_launch(void* const* d_in, const int* in_sizes, int n_in,
                              void* d_out, int out_size, void* d_ws,
                              size_t ws_size, hipStream_t stream) {
  (void)in_sizes; (void)n_in; (void)out_size; (void)ws_size;
  const float* hidden = (const float*)d_in[0];
  const float* mask   = (const float*)d_in[1];
  const float* Wq     = (const float*)d_in[2];
  const float* bq     = (const float*)d_in[3];
  const float* Wk     = (const float*)d_in[4];
  const float* bk     = (const float*)d_in[5];
  const float* Wv     = (const float*)d_in[6];
  const float* bv     = (const float*)d_in[7];
  float* out = (float*)d_out;

  uint8_t* w = (uint8_t*)d_ws;
  f16* Wt   = (f16*)(w);                               //  6 MB
  f16* X16  = (f16*)(w + (size_t)6 * 1024 * 1024);     // 16 MB
  f16* Q16  = (f16*)(w + (size_t)22 * 1024 * 1024);    // 16 MB (pre-scaled)
  f16* K16  = (f16*)(w + (size_t)38 * 1024 * 1024);    // 16 MB
  f16* Vt16 = (f16*)(w + (size_t)54 * 1024 * 1024);    // 16 MB, transposed

  cast_w_kernel<<<dim3(16, 16, 3), 256, 0, stream>>>(Wq, Wk, Wv, Wt);
  cast_x_kernel<<<4096, 256, 0, stream>>>(hidden, X16);
  qkv_gemm_kernel<<<dim3(1536), 256, 0, stream>>>(X16, Wt, bq, bk, bv,
                                                  Q16, K16, Vt16);
  flash_kernel<<<dim3(1024), 256, 0, stream>>>(Q16, K16, Vt16, mask, out);
}